// Round 1
// baseline (2376.974 us; speedup 1.0000x reference)
//
#include <hip/hip_runtime.h>

constexpr int B = 8, N = 1024, C = 768, H = 12, D = 64;
constexpr int M = B * N;          // 8192
constexpr int N_QKV = 3 * C;      // 2304
constexpr float SCALE = 0.125f;   // 1/sqrt(64)

static __device__ __forceinline__ unsigned short f2bf(float f) {
    unsigned u = __float_as_uint(f);
    u += 0x7fffu + ((u >> 16) & 1u);   // RNE
    return (unsigned short)(u >> 16);
}

// ---------------------------------------------------------------------------
// qkv = x @ w_qkv  (128x128 tile, 8x8 per thread), scatter epilogue to
// q/k/v workspaces in [B,H,N,D] layout.
// ---------------------------------------------------------------------------
__global__ __launch_bounds__(256)
void qkv_gemm(const float* __restrict__ A, const float* __restrict__ W,
              float* __restrict__ qws, float* __restrict__ kws, float* __restrict__ vws)
{
    __shared__ float As[16][132];
    __shared__ float Bs[16][132];
    const int t = threadIdx.x;
    const int mbase = blockIdx.y * 128;
    const int nbase = blockIdx.x * 128;
    const int tm = t & 15, tn = t >> 4;
    const int m0 = tm * 8, n0 = tn * 8;

    float acc[8][8] = {};

    for (int kb = 0; kb < C; kb += 16) {
        #pragma unroll
        for (int i = 0; i < 2; ++i) {
            int e4 = t + 256 * i;
            int am = e4 >> 2, k4 = (e4 & 3) * 4;
            float4 a = *(const float4*)(A + (size_t)(mbase + am) * C + kb + k4);
            As[k4 + 0][am] = a.x;
            As[k4 + 1][am] = a.y;
            As[k4 + 2][am] = a.z;
            As[k4 + 3][am] = a.w;
        }
        #pragma unroll
        for (int i = 0; i < 2; ++i) {
            int e4 = t + 256 * i;
            int bk = e4 >> 5, bn = (e4 & 31) * 4;
            *(float4*)&Bs[bk][bn] = *(const float4*)(W + (size_t)(kb + bk) * N_QKV + nbase + bn);
        }
        __syncthreads();
        #pragma unroll
        for (int kk = 0; kk < 16; ++kk) {
            float a[8], b[8];
            *(float4*)&a[0] = *(const float4*)&As[kk][m0];
            *(float4*)&a[4] = *(const float4*)&As[kk][m0 + 4];
            *(float4*)&b[0] = *(const float4*)&Bs[kk][n0];
            *(float4*)&b[4] = *(const float4*)&Bs[kk][n0 + 4];
            #pragma unroll
            for (int i = 0; i < 8; ++i)
                #pragma unroll
                for (int j = 0; j < 8; ++j)
                    acc[i][j] += a[i] * b[j];
        }
        __syncthreads();
    }

    const int seg = nbase / C;   // 768/128=6 tiles per segment -> uniform per block
    float* dst = (seg == 0) ? qws : (seg == 1) ? kws : vws;
    #pragma unroll
    for (int i = 0; i < 8; ++i) {
        int gm = mbase + m0 + i;
        int bb = gm >> 10, nn = gm & 1023;
        #pragma unroll
        for (int j = 0; j < 8; ++j) {
            int gn = nbase + n0 + j;
            int rem = gn - seg * C;
            int hh = rem >> 6, dd = rem & 63;
            dst[(((size_t)(bb * H + hh) << 10) + nn) * D + dd] = acc[i][j];
        }
    }
}

// ---------------------------------------------------------------------------
// Fused attention per (b,h, 8-row Q tile): QK^T -> softmax -> write attn ->
// PV -> write ctx[B,N,C].  Full 1024-wide score rows live in LDS (fp32).
// K chunk staged transposed in LDS as bf16.
// ---------------------------------------------------------------------------
__global__ __launch_bounds__(256)
void attn_kernel(const float* __restrict__ qws, const float* __restrict__ kws,
                 const float* __restrict__ vws, float* __restrict__ attn,
                 float* __restrict__ ctx)
{
    __shared__ float sP[8][1024];            // 32 KB score/prob rows
    __shared__ unsigned short sKT[64][132];  // 16.5 KB  K^T chunk (bf16), padded
    __shared__ float sQ[8][64];
    __shared__ float sInv[8];

    const int t = threadIdx.x;
    const int qt = blockIdx.x & 127;          // 128 q-tiles of 8 rows
    const int bh = blockIdx.x >> 7;           // 0..95
    const int row0 = qt * 8;
    const size_t kvbase = (size_t)bh * N * D;

    for (int i = t; i < 8 * 64; i += 256) {
        int r = i >> 6, d = i & 63;
        sQ[r][d] = qws[kvbase + (size_t)(row0 + r) * D + d];
    }
    __syncthreads();

    const int rr = t >> 5;           // this thread's Q row (0..7)
    const int jl = (t & 31) * 4;     // 4 keys within the 128-chunk
    float qreg[64];
    #pragma unroll
    for (int d = 0; d < 64; ++d) qreg[d] = sQ[rr][d];

    // ---- scores ----
    for (int jb = 0; jb < N; jb += 128) {
        if (jb) __syncthreads();
        for (int i = t; i < 128 * 64; i += 256) {
            int j = i >> 6, d = i & 63;
            sKT[d][j] = f2bf(kws[kvbase + (size_t)(jb + j) * D + d]);
        }
        __syncthreads();
        float a0 = 0.f, a1 = 0.f, a2 = 0.f, a3 = 0.f;
        #pragma unroll
        for (int d = 0; d < 64; ++d) {
            uint2 raw = *(const uint2*)&sKT[d][jl];
            float k0 = __uint_as_float(raw.x << 16);
            float k1 = __uint_as_float(raw.x & 0xffff0000u);
            float k2 = __uint_as_float(raw.y << 16);
            float k3 = __uint_as_float(raw.y & 0xffff0000u);
            float qd = qreg[d];
            a0 += qd * k0; a1 += qd * k1; a2 += qd * k2; a3 += qd * k3;
        }
        *(float4*)&sP[rr][jb + jl] =
            make_float4(a0 * SCALE, a1 * SCALE, a2 * SCALE, a3 * SCALE);
    }
    __syncthreads();

    // ---- softmax (8 rows x 32 threads each) ----
    {
        const int g = t >> 5, lane = t & 31;
        float mx = -1e30f;
        #pragma unroll
        for (int i = 0; i < 32; ++i) mx = fmaxf(mx, sP[g][lane + 32 * i]);
        #pragma unroll
        for (int off = 16; off >= 1; off >>= 1) mx = fmaxf(mx, __shfl_xor(mx, off));
        float sum = 0.f;
        #pragma unroll
        for (int i = 0; i < 32; ++i) {
            int j = lane + 32 * i;
            float p = __expf(sP[g][j] - mx);
            sP[g][j] = p;
            sum += p;
        }
        #pragma unroll
        for (int off = 16; off >= 1; off >>= 1) sum += __shfl_xor(sum, off);
        if (lane == 0) sInv[g] = 1.0f / sum;
    }
    __syncthreads();

    // ---- write normalized attn (float4, coalesced) ----
    {
        float4* dst = (float4*)(attn + (size_t)bh * N * N + (size_t)row0 * N);
        const float4* src = (const float4*)&sP[0][0];
        for (int i = t; i < 8 * 1024 / 4; i += 256) {
            int r = i >> 8;
            float4 p = src[i];
            float inv = sInv[r];
            p.x *= inv; p.y *= inv; p.z *= inv; p.w *= inv;
            dst[i] = p;
        }
    }

    // ---- PV: thread owns (d, rows rg & rg+4) ----
    {
        const int d = t & 63, rg = t >> 6;
        float acc0 = 0.f, acc1 = 0.f;
        const float* vb = vws + kvbase + d;
        #pragma unroll 4
        for (int j = 0; j < N; j += 4) {
            float4 pa = *(const float4*)&sP[rg][j];
            float4 pb = *(const float4*)&sP[rg + 4][j];
            float v0 = vb[(size_t)(j + 0) * D];
            float v1 = vb[(size_t)(j + 1) * D];
            float v2 = vb[(size_t)(j + 2) * D];
            float v3 = vb[(size_t)(j + 3) * D];
            acc0 += pa.x * v0 + pa.y * v1 + pa.z * v2 + pa.w * v3;
            acc1 += pb.x * v0 + pb.y * v1 + pb.z * v2 + pb.w * v3;
        }
        const int bb = bh / H, hh = bh - bb * H;
        ctx[((size_t)(bb * N + row0 + rg)) * C + hh * 64 + d] = acc0 * sInv[rg];
        ctx[((size_t)(bb * N + row0 + rg + 4)) * C + hh * 64 + d] = acc1 * sInv[rg + 4];
    }
}

// ---------------------------------------------------------------------------
// out = ctx @ w_proj + b_proj   (128x128 tile, 8x8 per thread)
// ---------------------------------------------------------------------------
__global__ __launch_bounds__(256)
void proj_gemm(const float* __restrict__ A, const float* __restrict__ W,
               const float* __restrict__ bias, float* __restrict__ out)
{
    __shared__ float As[16][132];
    __shared__ float Bs[16][132];
    const int t = threadIdx.x;
    const int mbase = blockIdx.y * 128;
    const int nbase = blockIdx.x * 128;
    const int tm = t & 15, tn = t >> 4;
    const int m0 = tm * 8, n0 = tn * 8;

    float acc[8][8] = {};

    for (int kb = 0; kb < C; kb += 16) {
        #pragma unroll
        for (int i = 0; i < 2; ++i) {
            int e4 = t + 256 * i;
            int am = e4 >> 2, k4 = (e4 & 3) * 4;
            float4 a = *(const float4*)(A + (size_t)(mbase + am) * C + kb + k4);
            As[k4 + 0][am] = a.x;
            As[k4 + 1][am] = a.y;
            As[k4 + 2][am] = a.z;
            As[k4 + 3][am] = a.w;
        }
        #pragma unroll
        for (int i = 0; i < 2; ++i) {
            int e4 = t + 256 * i;
            int bk = e4 >> 5, bn = (e4 & 31) * 4;
            *(float4*)&Bs[bk][bn] = *(const float4*)(W + (size_t)(kb + bk) * C + nbase + bn);
        }
        __syncthreads();
        #pragma unroll
        for (int kk = 0; kk < 16; ++kk) {
            float a[8], b[8];
            *(float4*)&a[0] = *(const float4*)&As[kk][m0];
            *(float4*)&a[4] = *(const float4*)&As[kk][m0 + 4];
            *(float4*)&b[0] = *(const float4*)&Bs[kk][n0];
            *(float4*)&b[4] = *(const float4*)&Bs[kk][n0 + 4];
            #pragma unroll
            for (int i = 0; i < 8; ++i)
                #pragma unroll
                for (int j = 0; j < 8; ++j)
                    acc[i][j] += a[i] * b[j];
        }
        __syncthreads();
    }

    #pragma unroll
    for (int i = 0; i < 8; ++i) {
        int gm = mbase + m0 + i;
        #pragma unroll
        for (int j = 0; j < 8; ++j) {
            int gn = nbase + n0 + j;
            out[(size_t)gm * C + gn] = acc[i][j] + bias[gn];
        }
    }
}

extern "C" void kernel_launch(void* const* d_in, const int* in_sizes, int n_in,
                              void* d_out, int out_size, void* d_ws, size_t ws_size,
                              hipStream_t stream)
{
    (void)in_sizes; (void)n_in; (void)out_size; (void)ws_size;
    const float* x      = (const float*)d_in[0];
    const float* w_qkv  = (const float*)d_in[1];
    const float* w_proj = (const float*)d_in[2];
    const float* b_proj = (const float*)d_in[3];

    float* out  = (float*)d_out;
    float* attn = out + (size_t)B * N * C;

    const size_t HND = (size_t)B * H * N * D;   // 6291456
    float* q   = (float*)d_ws;
    float* k   = q + HND;
    float* v   = k + HND;
    float* ctx = v + HND;

    qkv_gemm<<<dim3(N_QKV / 128, M / 128), 256, 0, stream>>>(x, w_qkv, q, k, v);
    attn_kernel<<<dim3(B * H * (N / 8)), 256, 0, stream>>>(q, k, v, attn, ctx);
    proj_gemm<<<dim3(C / 128, M / 128), 256, 0, stream>>>(ctx, w_proj, b_proj, out);
}

// Round 2
// 660.432 us; speedup vs baseline: 3.5991x; 3.5991x over previous
//
#include <hip/hip_runtime.h>
#include <stdint.h>

constexpr int B = 8, N = 1024, C = 768, H = 12, D = 64;
constexpr int M = B * N;          // 8192
constexpr int NQKV = 3 * C;       // 2304
constexpr float SCALE = 0.125f;   // 1/sqrt(64)

typedef _Float16 f16;
typedef _Float16 f16x8 __attribute__((ext_vector_type(8)));
typedef _Float16 f16x4 __attribute__((ext_vector_type(4)));
typedef float    f32x4 __attribute__((ext_vector_type(4)));

// global->LDS 16B DMA. LDS side: wave-uniform base, HW adds lane*16.
__device__ __forceinline__ void gl_lds16(const void* g, void* lds_base) {
    auto gp = (const __attribute__((address_space(1))) uint32_t*)(uintptr_t)g;
    auto lp = (__attribute__((address_space(3))) uint32_t*)(uint32_t)(uintptr_t)lds_base;
    __builtin_amdgcn_global_load_lds(gp, lp, 16, 0, 0);
}

// ---------------------------------------------------------------------------
// x (fp32) -> xh (fp16), elementwise
// ---------------------------------------------------------------------------
__global__ __launch_bounds__(256)
void conv_x_kernel(const float* __restrict__ x, f16* __restrict__ xh)
{
    size_t i = (size_t)blockIdx.x * 256 + threadIdx.x;
    float4 v = ((const float4*)x)[i];
    f16x4 h = { (f16)v.x, (f16)v.y, (f16)v.z, (f16)v.w };
    *(f16x4*)(xh + 4 * i) = h;
}

// ---------------------------------------------------------------------------
// src[rows][cols] fp32 -> dst[cols][rows] fp16  (32x32 LDS tile transpose)
// ---------------------------------------------------------------------------
__global__ __launch_bounds__(256)
void transpose_conv(const float* __restrict__ src, f16* __restrict__ dst,
                    int rows, int cols)
{
    __shared__ float tile[32][33];
    const int tx = threadIdx.x & 31, ty = threadIdx.x >> 5;
    const int bx = blockIdx.x * 32, by = blockIdx.y * 32;
    #pragma unroll
    for (int i = 0; i < 4; ++i)
        tile[ty + 8 * i][tx] = src[(size_t)(by + ty + 8 * i) * cols + bx + tx];
    __syncthreads();
    #pragma unroll
    for (int i = 0; i < 4; ++i)
        dst[(size_t)(bx + ty + 8 * i) * rows + by + tx] = (f16)tile[tx][ty + 8 * i];
}

// ---------------------------------------------------------------------------
// qkv GEMM: A[8192][768] fp16 @ Bt[2304][768]^T, 128x128 tile, BK=32, MFMA.
// Epilogue scatters to q,k [B,H,N,D] fp16 and v^T [B,H,D,N] fp16.
// ---------------------------------------------------------------------------
__global__ __launch_bounds__(256)
void qkv_gemm_h(const f16* __restrict__ A, const f16* __restrict__ Bt,
                f16* __restrict__ qh, f16* __restrict__ kh, f16* __restrict__ vth)
{
    __shared__ f16 Ah[128 * 32];
    __shared__ f16 Bh[128 * 32];
    const int t = threadIdx.x, w = t >> 6, l = t & 63;
    const int mbase = blockIdx.y * 128, nbase = blockIdx.x * 128;
    const int wm = (w >> 1) * 64, wn = (w & 1) * 64;
    const int fr = l & 15, fq = l >> 4;

    f32x4 acc[4][4];
    #pragma unroll
    for (int i = 0; i < 4; ++i)
        #pragma unroll
        for (int j = 0; j < 4; ++j) acc[i][j] = (f32x4){0.f, 0.f, 0.f, 0.f};

    for (int kb = 0; kb < 768; kb += 32) {
        #pragma unroll
        for (int i = 0; i < 2; ++i) {
            int p = w * 2 + i;
            int r = p * 16 + (l >> 2), c = l & 3;
            gl_lds16(A + (size_t)(mbase + r) * 768 + kb + c * 8, Ah + p * 512);
            gl_lds16(Bt + (size_t)(nbase + r) * 768 + kb + c * 8, Bh + p * 512);
        }
        __syncthreads();
        f16x8 af[4], bf[4];
        #pragma unroll
        for (int mt = 0; mt < 4; ++mt)
            af[mt] = *(const f16x8*)&Ah[(wm + mt * 16 + fr) * 32 + fq * 8];
        #pragma unroll
        for (int nt = 0; nt < 4; ++nt)
            bf[nt] = *(const f16x8*)&Bh[(wn + nt * 16 + fr) * 32 + fq * 8];
        #pragma unroll
        for (int mt = 0; mt < 4; ++mt)
            #pragma unroll
            for (int nt = 0; nt < 4; ++nt)
                acc[mt][nt] = __builtin_amdgcn_mfma_f32_16x16x32_f16(af[mt], bf[nt], acc[mt][nt], 0, 0, 0);
        __syncthreads();
    }

    const int seg = nbase / 768;      // 0=q 1=k 2=v, uniform per block
    #pragma unroll
    for (int mt = 0; mt < 4; ++mt) {
        int tok0 = mbase + wm + mt * 16 + fq * 4;
        int bb = tok0 >> 10, nn0 = tok0 & 1023;
        #pragma unroll
        for (int nt = 0; nt < 4; ++nt) {
            int od = nbase + wn + nt * 16 + fr;
            int rem = od - seg * 768;
            int hh = rem >> 6, dd = rem & 63;
            if (seg == 2) {
                f16x4 pv = { (f16)acc[mt][nt][0], (f16)acc[mt][nt][1],
                             (f16)acc[mt][nt][2], (f16)acc[mt][nt][3] };
                *(f16x4*)(vth + ((size_t)(bb * H + hh) * 64 + dd) * 1024 + nn0) = pv;
            } else {
                f16* dst = (seg == 0) ? qh : kh;
                size_t base = (size_t)(bb * H + hh) * 1024;
                #pragma unroll
                for (int rg = 0; rg < 4; ++rg)
                    dst[(base + nn0 + rg) * 64 + dd] = (f16)acc[mt][nt][rg];
            }
        }
    }
}

// ---------------------------------------------------------------------------
// Fused attention: one block per (b,h, 16 Q rows). S in registers (64/lane),
// cross-wave softmax, attn written from regs, P->LDS fp16 for PV MFMA.
// ---------------------------------------------------------------------------
__global__ __launch_bounds__(256)
void attn_fused(const f16* __restrict__ qh, const f16* __restrict__ kh,
                const f16* __restrict__ vth, float* __restrict__ attn,
                f16* __restrict__ ctxh)
{
    __shared__ f16 sQ[16 * 72];        // padded rows (144B, 16B-aligned)
    __shared__ f16 sKV[128 * 64];      // 16KB staged K chunk / V^T chunk (swizzled)
    __shared__ f16 sPh[16 * 1032];     // P fp16, padded rows (2064B = 16*129)
    __shared__ float sRed[2][4][16];

    const int t = threadIdx.x, w = t >> 6, l = t & 63;
    const int bh = blockIdx.x >> 6, qt = blockIdx.x & 63;
    const int row0 = qt * 16;
    const size_t kvbase = (size_t)bh * (1024 * 64);
    const int fr = l & 15, fq = l >> 4;

    // stage Q tile 16x64
    {
        int r = t >> 4, d4 = (t & 15) * 4;
        *(f16x4*)&sQ[r * 72 + d4] = *(const f16x4*)(qh + kvbase + (size_t)(row0 + r) * 64 + d4);
    }
    __syncthreads();

    f16x8 af[2];
    #pragma unroll
    for (int ks = 0; ks < 2; ++ks)
        af[ks] = *(const f16x8*)&sQ[fr * 72 + ks * 32 + fq * 8];

    f32x4 sacc[8][2];
    #pragma unroll
    for (int jc = 0; jc < 8; ++jc) {
        sacc[jc][0] = (f32x4){0.f, 0.f, 0.f, 0.f};
        sacc[jc][1] = (f32x4){0.f, 0.f, 0.f, 0.f};
    }

    // ---- S = Q K^T : stream K in 128-key chunks ----
    for (int jc = 0; jc < 8; ++jc) {
        #pragma unroll
        for (int i = 0; i < 4; ++i) {
            int p = w * 4 + i;
            int r = p * 8 + (l >> 3);
            int c = (l & 7) ^ (r & 7);               // xor-swizzled 16B chunk
            gl_lds16(kh + kvbase + (size_t)(jc * 128 + r) * 64 + c * 8, sKV + p * 512);
        }
        __syncthreads();
        #pragma unroll
        for (int nt2 = 0; nt2 < 2; ++nt2) {
            int brow = w * 32 + nt2 * 16 + fr;
            #pragma unroll
            for (int ks = 0; ks < 2; ++ks) {
                int cc = (ks * 4 + fq) ^ (brow & 7);
                f16x8 bf = *(const f16x8*)&sKV[brow * 64 + cc * 8];
                sacc[jc][nt2] = __builtin_amdgcn_mfma_f32_16x16x32_f16(af[ks], bf, sacc[jc][nt2], 0, 0, 0);
            }
        }
        __syncthreads();
    }

    // ---- softmax over full 1024-wide rows (rows fq*4+r of this Q tile) ----
    float mrow[4] = {-1e30f, -1e30f, -1e30f, -1e30f};
    #pragma unroll
    for (int jc = 0; jc < 8; ++jc)
        #pragma unroll
        for (int nt2 = 0; nt2 < 2; ++nt2)
            #pragma unroll
            for (int r = 0; r < 4; ++r)
                mrow[r] = fmaxf(mrow[r], sacc[jc][nt2][r]);
    #pragma unroll
    for (int off = 1; off < 16; off <<= 1)
        #pragma unroll
        for (int r = 0; r < 4; ++r)
            mrow[r] = fmaxf(mrow[r], __shfl_xor(mrow[r], off));
    if (fr == 0)
        #pragma unroll
        for (int r = 0; r < 4; ++r) sRed[0][w][fq * 4 + r] = mrow[r];
    __syncthreads();

    float Mv[4];
    #pragma unroll
    for (int r = 0; r < 4; ++r) {
        int row = fq * 4 + r;
        float m = fmaxf(fmaxf(sRed[0][0][row], sRed[0][1][row]),
                        fmaxf(sRed[0][2][row], sRed[0][3][row]));
        Mv[r] = m * SCALE;
    }
    float srow[4] = {0.f, 0.f, 0.f, 0.f};
    #pragma unroll
    for (int jc = 0; jc < 8; ++jc)
        #pragma unroll
        for (int nt2 = 0; nt2 < 2; ++nt2)
            #pragma unroll
            for (int r = 0; r < 4; ++r) {
                float p = __expf(sacc[jc][nt2][r] * SCALE - Mv[r]);
                sacc[jc][nt2][r] = p;
                srow[r] += p;
            }
    #pragma unroll
    for (int off = 1; off < 16; off <<= 1)
        #pragma unroll
        for (int r = 0; r < 4; ++r)
            srow[r] += __shfl_xor(srow[r], off);
    if (fr == 0)
        #pragma unroll
        for (int r = 0; r < 4; ++r) sRed[1][w][fq * 4 + r] = srow[r];
    __syncthreads();

    float inv[4];
    #pragma unroll
    for (int r = 0; r < 4; ++r) {
        int row = fq * 4 + r;
        inv[r] = 1.0f / (sRed[1][0][row] + sRed[1][1][row] + sRed[1][2][row] + sRed[1][3][row]);
    }

    // ---- write attn (fp32) from regs + P (fp16) to LDS ----
    float* ab = attn + ((size_t)bh << 20) + (size_t)row0 * 1024;
    #pragma unroll
    for (int jc = 0; jc < 8; ++jc)
        #pragma unroll
        for (int nt2 = 0; nt2 < 2; ++nt2) {
            int col = jc * 128 + w * 32 + nt2 * 16 + fr;
            #pragma unroll
            for (int r = 0; r < 4; ++r) {
                int row = fq * 4 + r;
                float pv = sacc[jc][nt2][r] * inv[r];
                ab[(size_t)row * 1024 + col] = pv;
                sPh[row * 1032 + col] = (f16)pv;
            }
        }
    __syncthreads();

    // ---- O = P V : stream V^T in 128-key chunks, wave w owns dims [16w,16w+16) ----
    f32x4 oacc = (f32x4){0.f, 0.f, 0.f, 0.f};
    for (int jc = 0; jc < 8; ++jc) {
        #pragma unroll
        for (int i = 0; i < 4; ++i) {
            int p = w * 4 + i;
            int r = p * 4 + (l >> 4);                // d row (0..63)
            int c = (l & 15) ^ (r & 15);             // swizzled 16B chunk (16/row)
            gl_lds16(vth + kvbase + (size_t)r * 1024 + jc * 128 + c * 8, sKV + p * 512);
        }
        __syncthreads();
        #pragma unroll
        for (int ks = 0; ks < 4; ++ks) {
            f16x8 pf = *(const f16x8*)&sPh[fr * 1032 + jc * 128 + ks * 32 + fq * 8];
            int brow = w * 16 + fr;
            int cc = (ks * 4 + fq) ^ (brow & 15);
            f16x8 vf = *(const f16x8*)&sKV[brow * 128 + cc * 8];
            oacc = __builtin_amdgcn_mfma_f32_16x16x32_f16(pf, vf, oacc, 0, 0, 0);
        }
        __syncthreads();
    }

    const int bb = bh / H, hh = bh - bb * H;
    int tok0 = bb * 1024 + row0 + fq * 4;
    int cd = hh * 64 + w * 16 + fr;
    #pragma unroll
    for (int rg = 0; rg < 4; ++rg)
        ctxh[(size_t)(tok0 + rg) * 768 + cd] = (f16)oacc[rg];
}

// ---------------------------------------------------------------------------
// out = ctx @ w_proj + b_proj  (fp16 MFMA, fp32 out)
// ---------------------------------------------------------------------------
__global__ __launch_bounds__(256)
void proj_gemm_h(const f16* __restrict__ A, const f16* __restrict__ Bt,
                 const float* __restrict__ bias, float* __restrict__ out)
{
    __shared__ f16 Ah[128 * 32];
    __shared__ f16 Bh[128 * 32];
    const int t = threadIdx.x, w = t >> 6, l = t & 63;
    const int mbase = blockIdx.y * 128, nbase = blockIdx.x * 128;
    const int wm = (w >> 1) * 64, wn = (w & 1) * 64;
    const int fr = l & 15, fq = l >> 4;

    f32x4 acc[4][4];
    #pragma unroll
    for (int i = 0; i < 4; ++i)
        #pragma unroll
        for (int j = 0; j < 4; ++j) acc[i][j] = (f32x4){0.f, 0.f, 0.f, 0.f};

    for (int kb = 0; kb < 768; kb += 32) {
        #pragma unroll
        for (int i = 0; i < 2; ++i) {
            int p = w * 2 + i;
            int r = p * 16 + (l >> 2), c = l & 3;
            gl_lds16(A + (size_t)(mbase + r) * 768 + kb + c * 8, Ah + p * 512);
            gl_lds16(Bt + (size_t)(nbase + r) * 768 + kb + c * 8, Bh + p * 512);
        }
        __syncthreads();
        f16x8 af[4], bf[4];
        #pragma unroll
        for (int mt = 0; mt < 4; ++mt)
            af[mt] = *(const f16x8*)&Ah[(wm + mt * 16 + fr) * 32 + fq * 8];
        #pragma unroll
        for (int nt = 0; nt < 4; ++nt)
            bf[nt] = *(const f16x8*)&Bh[(wn + nt * 16 + fr) * 32 + fq * 8];
        #pragma unroll
        for (int mt = 0; mt < 4; ++mt)
            #pragma unroll
            for (int nt = 0; nt < 4; ++nt)
                acc[mt][nt] = __builtin_amdgcn_mfma_f32_16x16x32_f16(af[mt], bf[nt], acc[mt][nt], 0, 0, 0);
        __syncthreads();
    }

    #pragma unroll
    for (int mt = 0; mt < 4; ++mt) {
        int tok0 = mbase + wm + mt * 16 + fq * 4;
        #pragma unroll
        for (int nt = 0; nt < 4; ++nt) {
            int od = nbase + wn + nt * 16 + fr;
            float bv = bias[od];
            #pragma unroll
            for (int rg = 0; rg < 4; ++rg)
                out[(size_t)(tok0 + rg) * 768 + od] = acc[mt][nt][rg] + bv;
        }
    }
}

extern "C" void kernel_launch(void* const* d_in, const int* in_sizes, int n_in,
                              void* d_out, int out_size, void* d_ws, size_t ws_size,
                              hipStream_t stream)
{
    (void)in_sizes; (void)n_in; (void)out_size; (void)ws_size;
    const float* x      = (const float*)d_in[0];
    const float* w_qkv  = (const float*)d_in[1];
    const float* w_proj = (const float*)d_in[2];
    const float* b_proj = (const float*)d_in[3];

    float* out  = (float*)d_out;
    float* attn = out + (size_t)B * N * C;

    const size_t HND = (size_t)B * H * N * D;   // 6291456
    f16* xh     = (f16*)d_ws;
    f16* wqkvT  = xh + HND;                     // 2304*768 = 1769472
    f16* wprojT = wqkvT + 1769472;              // 768*768  = 589824
    f16* qh     = wprojT + 589824;
    f16* kh     = qh + HND;
    f16* vth    = kh + HND;
    f16* ctxh   = vth + HND;

    conv_x_kernel<<<dim3(6144), 256, 0, stream>>>(x, xh);
    transpose_conv<<<dim3(NQKV / 32, C / 32), 256, 0, stream>>>(w_qkv, wqkvT, C, NQKV);
    transpose_conv<<<dim3(C / 32, C / 32), 256, 0, stream>>>(w_proj, wprojT, C, C);
    qkv_gemm_h<<<dim3(NQKV / 128, M / 128), 256, 0, stream>>>(xh, wqkvT, qh, kh, vth);
    attn_fused<<<dim3(B * H * (N / 16)), 256, 0, stream>>>(qh, kh, vth, attn, ctxh);
    proj_gemm_h<<<dim3(C / 128, M / 128), 256, 0, stream>>>(ctxh, wprojT, b_proj, out);
}